// Round 13
// baseline (300.844 us; speedup 1.0000x reference)
//
#include <hip/hip_runtime.h>
#include <hip/hip_bf16.h>

// Problem constants
#define D_NODES 128
#define KD      128   // x feature dim (K of GEMM1)
#define M1_     256
#define M2_     128
#define B_      4096
#define BM      128   // batch rows per block (16 per wave)
#define CI      64    // i-chunk of M1
#define NCH     4     // M1/CI
#define LOG2E   1.44269504088896f

typedef short bf16x8  __attribute__((ext_vector_type(8)));
typedef short short4v __attribute__((ext_vector_type(4)));
typedef float f32x4   __attribute__((ext_vector_type(4)));
typedef unsigned int uint2v __attribute__((ext_vector_type(2)));

#define MFMA16(a, b, c) __builtin_amdgcn_mfma_f32_16x16x32_bf16((a), (b), (c), 0, 0, 0)

__device__ __forceinline__ short f2b(float f) {
  unsigned u = __builtin_bit_cast(unsigned, f);
  u += 0x7FFFu + ((u >> 16) & 1u);
  return (short)(u >> 16);
}

__device__ __forceinline__ float sigmoid_pre(float acc, float bs) {
  // bs = -log2e * bias ; returns sigmoid(acc + bias)
  float tt = __builtin_fmaf(acc, -LOG2E, bs);
  float e = __builtin_amdgcn_exp2f(tt);
  return __builtin_amdgcn_rcpf(1.0f + e);
}

// 4 sigmoids -> 4 bf16 (RNE) packed as short4v via __float22bfloat162_rn.
__device__ __forceinline__ short4v pack_sig4(f32x4 a, f32x4 bs) {
  float s0 = sigmoid_pre(a[0], bs[0]);
  float s1 = sigmoid_pre(a[1], bs[1]);
  float s2 = sigmoid_pre(a[2], bs[2]);
  float s3 = sigmoid_pre(a[3], bs[3]);
  __hip_bfloat162 h01 = __float22bfloat162_rn(make_float2(s0, s1));
  __hip_bfloat162 h23 = __float22bfloat162_rn(make_float2(s2, s3));
  uint2v uv;
  unsigned u0, u1;
  __builtin_memcpy(&u0, &h01, 4);
  __builtin_memcpy(&u1, &h23, 4);
  uv[0] = u0;
  uv[1] = u1;
  return __builtin_bit_cast(short4v, uv);
}

// ---- pre-pass kernels ----
__global__ void cvt_f2b_k(const float* __restrict__ in, short* __restrict__ out) {
  int i = (blockIdx.x * 256 + threadIdx.x) * 4;
  float4 f = *(const float4*)(in + i);
  short4v s; s[0] = f2b(f.x); s[1] = f2b(f.y); s[2] = f2b(f.z); s[3] = f2b(f.w);
  *(short4v*)(out + i) = s;
}

// Wa [node][i=256][o=128] fp32 -> waT [node][o=128][i=256] bf16 (plain layout)
__global__ void trans_wa_k(const float* __restrict__ Wa, short* __restrict__ waT) {
  __shared__ float lt[64][129];
  int node = blockIdx.x >> 2, iblk = blockIdx.x & 3;
  int t = threadIdx.x;
  for (int j = 0; j < 32; ++j) {
    int e = j * 256 + t;
    int i = e >> 7, o = e & 127;
    lt[i][o] = Wa[(node * M1_ + iblk * 64 + i) * M2_ + o];
  }
  __syncthreads();
  int il = t & 63, ob = t >> 6;
  for (int j = 0; j < 32; ++j) {
    int o = j * 4 + ob;
    waT[(node * M2_ + o) * M1_ + iblk * 64 + il] = f2b(lt[il][o]);
  }
}

// ---- fused main kernel ----
// 16-row waves -> acc2 32 regs -> <=128 total regs (launch_bounds 512,4)
// -> 4 waves/SIMD (16 waves/CU, 2 blocks/CU). LDS = 48KB/block: W1 staged
// in 32KB HALVES (restaged once, 2 extra barriers); Wa streamed from global
// (L2-resident per XCD), kk0 hoisted before G1, kk1 issued under sigmoid.
template <bool FAST>
__global__ __launch_bounds__(512, 4)
void fused_dag_k(const float* __restrict__ x,  const float* __restrict__ W1,
                 const float* __restrict__ b1, const float* __restrict__ Wa,
                 const float* __restrict__ ba, const float* __restrict__ Wb,
                 const float* __restrict__ bb, float* __restrict__ out,
                 const short* __restrict__ w1b, const short* __restrict__ waT,
                 const short* __restrict__ xb) {
  __shared__ __align__(16) short w1s[128 * KD];    // 32KB: one i-half, swizzled
  __shared__ __align__(16) short h1w[8 * 16 * CI]; // 16KB: per-wave [16][64] swizzled

  int gid = blockIdx.x;
  int xcd = gid & 7, ii = gid >> 3;     // ii 0..511
  int node = xcd * 16 + (ii >> 5);      // nodes grouped per XCD for L2 reuse
  int tile = ii & 31;
  int b0 = tile * BM;

  int t = threadIdx.x;
  int w = t >> 6, l = t & 63;
  int n15 = l & 15, q = l >> 4;

  // ---- x B-frags for this wave's 16 rows ----
  bf16x8 xa[4];
  {
    int row = b0 + w * 16 + n15;
#pragma unroll
    for (int kk = 0; kk < 4; ++kk) {
      int k0 = kk * 32 + q * 8;
      if (FAST) {
        xa[kk] = *(const bf16x8*)(xb + row * KD + k0);
      } else {
        float4 f0 = *(const float4*)(x + row * KD + k0);
        float4 f1 = *(const float4*)(x + row * KD + k0 + 4);
        bf16x8 v;
        v[0] = f2b(f0.x); v[1] = f2b(f0.y); v[2] = f2b(f0.z); v[3] = f2b(f0.w);
        v[4] = f2b(f1.x); v[5] = f2b(f1.y); v[6] = f2b(f1.z); v[7] = f2b(f1.w);
        xa[kk] = v;
      }
    }
  }

  // ---- hoisted swizzle address bases (byte offsets, int) ----
  int swz = n15 & 7;
  int hsw = (swz >> 2) << 6;
  int qx16 = (q ^ (swz & 3)) << 4;
  int swd32 = (swz >> 1) << 5;
  int qhx = ((q >> 1) ^ (swz & 1)) << 4;
  int qlo8 = (q & 1) << 3;

  const char* w1c8 = (const char*)w1s;
  char* h1c8 = (char*)h1w;

  int w1o = n15 * 256 + qx16 + hsw;            // + cl*16384 ^ (kk<<6) + it*4096
  int h1wo = w * 2048 + n15 * 128 + qlo8 + qhx + swd32;  // ^ (it<<5)
  int h1ro = w * 2048 + n15 * 128 + qx16 + hsw;          // ^ (kk<<6)

  const short* w1n = w1b + (size_t)node * (M1_ * KD);
  const short* wan = waT + (size_t)node * (M2_ * M1_);
  const float* b1n = b1 + node * M1_;

  f32x4 acc2[8];
#pragma unroll
  for (int b = 0; b < 8; ++b) acc2[b] = (f32x4){0.f, 0.f, 0.f, 0.f};

  for (int h = 0; h < 2; ++h) {
    // ---- stage W1 i-half h (reg-staged, swizzled writes) ----
    if (h) __syncthreads();  // all waves done reading previous half
    if (FAST) {
#pragma unroll
      for (int j = 0; j < 4; ++j) {
        int s = j * 512 + t;
        int row = s >> 4, g = s & 15;
        bf16x8 v = *(const bf16x8*)(w1n + (h * 128 + row) * KD + g * 8);
        *(bf16x8*)(&w1s[row * KD + ((g ^ (row & 7)) << 3)]) = v;
      }
    } else {
#pragma unroll
      for (int j = 0; j < 4; ++j) {
        int s = j * 512 + t;
        int row = s >> 4, g = s & 15;
        const float* src = W1 + ((size_t)node * M1_ + h * 128 + row) * KD + g * 8;
        float4 f0 = *(const float4*)(src);
        float4 f1 = *(const float4*)(src + 4);
        bf16x8 v;
        v[0] = f2b(f0.x); v[1] = f2b(f0.y); v[2] = f2b(f0.z); v[3] = f2b(f0.w);
        v[4] = f2b(f1.x); v[5] = f2b(f1.y); v[6] = f2b(f1.z); v[7] = f2b(f1.w);
        *(bf16x8*)(&w1s[row * KD + ((g ^ (row & 7)) << 3)]) = v;
      }
    }
    __syncthreads();

    for (int cl = 0; cl < 2; ++cl) {
      int c = h * 2 + cl;

      // wa kk=0 fragments: issue FIRST (global; latency hides under G1)
      bf16x8 wa0[8];
#pragma unroll
      for (int ot = 0; ot < 8; ++ot) {
        if (FAST) {
          wa0[ot] = *(const bf16x8*)(wan + (ot * 16 + n15) * M1_ + c * CI + q * 8);
        } else {
          bf16x8 v;
#pragma unroll
          for (int e = 0; e < 8; ++e)
            v[e] = f2b(Wa[((size_t)node * M1_ + c * CI + q * 8 + e) * M2_ +
                          (ot * 16 + n15)]);
          wa0[ot] = v;
        }
      }

      // bias (broadcast L1-hot)
      f32x4 bs[4];
      const float* b1c = b1n + c * CI;
#pragma unroll
      for (int it = 0; it < 4; ++it)
        bs[it] = (*(const f32x4*)(b1c + it * 16 + q * 4)) * (-LOG2E);

      // GEMM1: C1[i=64][b=16]; 16 MFMA
      f32x4 acc1[4];
#pragma unroll
      for (int a = 0; a < 4; ++a) acc1[a] = (f32x4){0.f, 0.f, 0.f, 0.f};
      int w1base = w1o + cl * 16384;
#pragma unroll
      for (int kk = 0; kk < 4; ++kk) {
        int p = w1base ^ (kk << 6);
#pragma unroll
        for (int it = 0; it < 4; ++it) {
          bf16x8 wf = *(const bf16x8*)(w1c8 + p + it * 4096);
          acc1[it] = MFMA16(wf, xa[kk], acc1[it]);
        }
      }

      // sigmoid + pack (VALU phase also covers wa1 issue below)
      short4v s4[4];
#pragma unroll
      for (int it = 0; it < 4; ++it) s4[it] = pack_sig4(acc1[it], bs[it]);

      // wa kk=1 fragments: issue now, consumed after G2(kk0)
      bf16x8 wa1[8];
#pragma unroll
      for (int ot = 0; ot < 8; ++ot) {
        if (FAST) {
          wa1[ot] =
              *(const bf16x8*)(wan + (ot * 16 + n15) * M1_ + c * CI + 32 + q * 8);
        } else {
          bf16x8 v;
#pragma unroll
          for (int e = 0; e < 8; ++e)
            v[e] = f2b(Wa[((size_t)node * M1_ + c * CI + 32 + q * 8 + e) * M2_ +
                          (ot * 16 + n15)]);
          wa1[ot] = v;
        }
      }

      // h1 write (4 b64) then read (2 b128); in-order DS per wave => RAW safe
#pragma unroll
      for (int it = 0; it < 4; ++it)
        *(short4v*)(h1c8 + (h1wo ^ (it << 5))) = s4[it];
      bf16x8 ha[2];
#pragma unroll
      for (int kk = 0; kk < 2; ++kk)
        ha[kk] = *(const bf16x8*)(h1c8 + (h1ro ^ (kk << 6)));

      // GEMM2: C2[b=16][o=128]; 16 MFMA
#pragma unroll
      for (int ot = 0; ot < 8; ++ot)
        acc2[ot] = MFMA16(ha[0], wa0[ot], acc2[ot]);
#pragma unroll
      for (int ot = 0; ot < 8; ++ot)
        acc2[ot] = MFMA16(ha[1], wa1[ot], acc2[ot]);
    }
  }

  // ---- epilogue: sigmoid(h2 + ba) * Wb, reduce over o, store ----
  const float* ban = ba + node * M2_;
  const float* wbn = Wb + node * M2_;
  float bbv = bb[node];
  f32x4 rs = (f32x4){0.f, 0.f, 0.f, 0.f};
#pragma unroll
  for (int ot = 0; ot < 8; ++ot) {
    int o = ot * 16 + n15;
    float bav = ban[o] * (-LOG2E);
    float wbv = wbn[o];
#pragma unroll
    for (int r = 0; r < 4; ++r)
      rs[r] += sigmoid_pre(acc2[ot][r], bav) * wbv;
  }
#pragma unroll
  for (int r = 0; r < 4; ++r) {
    float v = rs[r];
    v += __shfl_xor(v, 1);
    v += __shfl_xor(v, 2);
    v += __shfl_xor(v, 4);
    v += __shfl_xor(v, 8);
    if (n15 == 0)
      out[(size_t)(b0 + w * 16 + q * 4 + r) * D_NODES + node] = v + bbv;
  }
}

extern "C" void kernel_launch(void* const* d_in, const int* in_sizes, int n_in,
                              void* d_out, int out_size, void* d_ws, size_t ws_size,
                              hipStream_t stream) {
  const float* x  = (const float*)d_in[0];
  const float* W1 = (const float*)d_in[1];
  const float* b1 = (const float*)d_in[2];
  const float* Wa = (const float*)d_in[3];
  const float* ba = (const float*)d_in[4];
  const float* Wb = (const float*)d_in[5];
  const float* bb = (const float*)d_in[6];
  float* out = (float*)d_out;

  const size_t W1_ELEMS = (size_t)D_NODES * M1_ * KD;   // 4194304
  const size_t WA_ELEMS = (size_t)D_NODES * M1_ * M2_;  // 4194304
  const size_t X_ELEMS  = (size_t)B_ * KD;              // 524288
  const size_t NEED = (W1_ELEMS + WA_ELEMS + X_ELEMS) * sizeof(short);

  const int GRID = D_NODES * (B_ / BM);  // 4096

  if (ws_size >= NEED) {
    short* w1b = (short*)d_ws;
    short* waT = w1b + W1_ELEMS;
    short* xb  = waT + WA_ELEMS;
    cvt_f2b_k<<<(int)(W1_ELEMS / 1024), 256, 0, stream>>>(W1, w1b);
    cvt_f2b_k<<<(int)(X_ELEMS / 1024), 256, 0, stream>>>(x, xb);
    trans_wa_k<<<D_NODES * 4, 256, 0, stream>>>(Wa, waT);
    fused_dag_k<true><<<GRID, 512, 0, stream>>>(x, W1, b1, Wa, ba, Wb, bb, out,
                                                w1b, waT, xb);
  } else {
    fused_dag_k<false><<<GRID, 512, 0, stream>>>(x, W1, b1, Wa, ba, Wb, bb, out,
                                                 nullptr, nullptr, nullptr);
  }
}

// Round 14
// 125.725 us; speedup vs baseline: 2.3929x; 2.3929x over previous
//
#include <hip/hip_runtime.h>
#include <hip/hip_bf16.h>

// Problem constants
#define D_NODES 128
#define KD      128   // x feature dim (K of GEMM1)
#define M1_     256
#define M2_     128
#define B_      4096
#define BM      256   // batch rows per block
#define CI      64    // i-chunk of M1
#define NCH     4     // M1/CI
#define LOG2E   1.44269504088896f

typedef short bf16x8  __attribute__((ext_vector_type(8)));
typedef short short4v __attribute__((ext_vector_type(4)));
typedef float f32x4   __attribute__((ext_vector_type(4)));
typedef unsigned int uint2v __attribute__((ext_vector_type(2)));

#define MFMA16(a, b, c) __builtin_amdgcn_mfma_f32_16x16x32_bf16((a), (b), (c), 0, 0, 0)

__device__ __forceinline__ short f2b(float f) {
  unsigned u = __builtin_bit_cast(unsigned, f);
  u += 0x7FFFu + ((u >> 16) & 1u);
  return (short)(u >> 16);
}

__device__ __forceinline__ float sigmoid_pre(float acc, float bs) {
  // bs = -log2e * bias ; returns sigmoid(acc + bias)
  float tt = __builtin_fmaf(acc, -LOG2E, bs);
  float e = __builtin_amdgcn_exp2f(tt);
  return __builtin_amdgcn_rcpf(1.0f + e);
}

// 4 sigmoids -> 4 bf16 (RNE) packed as short4v via __float22bfloat162_rn.
__device__ __forceinline__ short4v pack_sig4(f32x4 a, f32x4 bs) {
  float s0 = sigmoid_pre(a[0], bs[0]);
  float s1 = sigmoid_pre(a[1], bs[1]);
  float s2 = sigmoid_pre(a[2], bs[2]);
  float s3 = sigmoid_pre(a[3], bs[3]);
  __hip_bfloat162 h01 = __float22bfloat162_rn(make_float2(s0, s1));
  __hip_bfloat162 h23 = __float22bfloat162_rn(make_float2(s2, s3));
  uint2v uv;
  unsigned u0, u1;
  __builtin_memcpy(&u0, &h01, 4);
  __builtin_memcpy(&u1, &h23, 4);
  uv[0] = u0;
  uv[1] = u1;
  return __builtin_bit_cast(short4v, uv);
}

// ---- pre-pass kernels ----
__global__ void cvt_f2b_k(const float* __restrict__ in, short* __restrict__ out) {
  int i = (blockIdx.x * 256 + threadIdx.x) * 4;
  float4 f = *(const float4*)(in + i);
  short4v s; s[0] = f2b(f.x); s[1] = f2b(f.y); s[2] = f2b(f.z); s[3] = f2b(f.w);
  *(short4v*)(out + i) = s;
}

// Wa [node][i=256][o=128] fp32 -> waT [node][o=128][i=256] bf16 (plain layout)
__global__ void trans_wa_k(const float* __restrict__ Wa, short* __restrict__ waT) {
  __shared__ float lt[64][129];
  int node = blockIdx.x >> 2, iblk = blockIdx.x & 3;
  int t = threadIdx.x;
  for (int j = 0; j < 32; ++j) {
    int e = j * 256 + t;
    int i = e >> 7, o = e & 127;
    lt[i][o] = Wa[(node * M1_ + iblk * 64 + i) * M2_ + o];
  }
  __syncthreads();
  int il = t & 63, ob = t >> 6;
  for (int j = 0; j < 32; ++j) {
    int o = j * 4 + ob;
    waT[(node * M2_ + o) * M1_ + iblk * 64 + il] = f2b(lt[il][o]);
  }
}

// ---- fused main kernel (round-9 best: 126.0 us) ----
// All-LDS weights staged once (XOR-swizzled), barrier-free main loop,
// per-wave private h1, wa-fragment reads hoisted above GEMM1, hoisted
// XOR-decomposed addresses, packed bf16 conversion.
template <bool FAST>
__global__ __launch_bounds__(512, 2)
void fused_dag_k(const float* __restrict__ x,  const float* __restrict__ W1,
                 const float* __restrict__ b1, const float* __restrict__ Wa,
                 const float* __restrict__ ba, const float* __restrict__ Wb,
                 const float* __restrict__ bb, float* __restrict__ out,
                 const short* __restrict__ w1b, const short* __restrict__ waT,
                 const short* __restrict__ xb) {
  __shared__ __align__(16) short w1s[M1_ * KD];    // 64KB, swizzled
  __shared__ __align__(16) short was[M2_ * M1_];   // 64KB, swizzled
  __shared__ __align__(16) short h1w[8 * 16 * CI]; // 16KB per-wave [16][64] swizzled

  int gid = blockIdx.x;
  int xcd = gid & 7, ii = gid >> 3;
  int node = xcd * 16 + (ii >> 4);   // nodes grouped per XCD for L2 reuse
  int tile = ii & 15;
  int b0 = tile * BM;

  int t = threadIdx.x;
  int w = t >> 6, l = t & 63;
  int n15 = l & 15, q = l >> 4;

  // ---- stage weights (reg-staged: linear coalesced loads, swizzled writes) ----
  if (FAST) {
    const short* w1n = w1b + (size_t)node * (M1_ * KD);
    const short* wan = waT + (size_t)node * (M2_ * M1_);
    bf16x8 t1[8], t2[8];
#pragma unroll
    for (int j = 0; j < 8; ++j) t1[j] = *(const bf16x8*)(w1n + (j * 512 + t) * 8);
#pragma unroll
    for (int j = 0; j < 8; ++j) t2[j] = *(const bf16x8*)(wan + (j * 512 + t) * 8);
#pragma unroll
    for (int j = 0; j < 8; ++j) {
      int s = j * 512 + t;
      int row = s >> 4, g = s & 15;
      *(bf16x8*)(&w1s[row * KD + ((g ^ (row & 7)) << 3)]) = t1[j];
    }
#pragma unroll
    for (int j = 0; j < 8; ++j) {
      int s = j * 512 + t;
      int row = s >> 5, g = s & 31;
      *(bf16x8*)(&was[row * M1_ + ((g ^ (row & 7)) << 3)]) = t2[j];
    }
  } else {
#pragma unroll
    for (int j = 0; j < 8; ++j) {
      int s = j * 512 + t;
      int row = s >> 4, g = s & 15;
      const float* src = W1 + ((size_t)node * M1_ + row) * KD + g * 8;
      float4 f0 = *(const float4*)(src);
      float4 f1 = *(const float4*)(src + 4);
      bf16x8 v;
      v[0] = f2b(f0.x); v[1] = f2b(f0.y); v[2] = f2b(f0.z); v[3] = f2b(f0.w);
      v[4] = f2b(f1.x); v[5] = f2b(f1.y); v[6] = f2b(f1.z); v[7] = f2b(f1.w);
      *(bf16x8*)(&w1s[row * KD + ((g ^ (row & 7)) << 3)]) = v;
    }
    for (int j = 0; j < 8; ++j) {
      int s = j * 512 + t;
      int o = s >> 5, g = s & 31;
      bf16x8 v;
#pragma unroll
      for (int e = 0; e < 8; ++e)
        v[e] = f2b(Wa[((size_t)node * M1_ + g * 8 + e) * M2_ + o]);
      *(bf16x8*)(&was[o * M1_ + ((g ^ (o & 7)) << 3)]) = v;
    }
  }

  // ---- x B-frags for this wave's 32 rows ----
  bf16x8 xa[2][4];
  {
    int rb = b0 + w * 32;
#pragma unroll
    for (int mt = 0; mt < 2; ++mt) {
      int row = rb + mt * 16 + n15;
#pragma unroll
      for (int kk = 0; kk < 4; ++kk) {
        int k0 = kk * 32 + q * 8;
        if (FAST) {
          xa[mt][kk] = *(const bf16x8*)(xb + row * KD + k0);
        } else {
          float4 f0 = *(const float4*)(x + row * KD + k0);
          float4 f1 = *(const float4*)(x + row * KD + k0 + 4);
          bf16x8 v;
          v[0] = f2b(f0.x); v[1] = f2b(f0.y); v[2] = f2b(f0.z); v[3] = f2b(f0.w);
          v[4] = f2b(f1.x); v[5] = f2b(f1.y); v[6] = f2b(f1.z); v[7] = f2b(f1.w);
          xa[mt][kk] = v;
        }
      }
    }
  }

  __syncthreads();  // the ONLY barrier

  // ---- hoisted swizzle address bases (byte offsets, int) ----
  int swz = n15 & 7;
  int hsw = (swz >> 2) << 6;
  int qx16 = (q ^ (swz & 3)) << 4;
  int swd32 = (swz >> 1) << 5;
  int qhx = ((q >> 1) ^ (swz & 1)) << 4;
  int qlo8 = (q & 1) << 3;

  const char* w1c8 = (const char*)w1s;
  const char* wac8 = (const char*)was;
  char* h1c8 = (char*)h1w;

  int w1o = n15 * 256 + qx16 + hsw;             // + c*16384 ^ (kk<<6) + it*4096
  int wao = n15 * 512 + qx16 + hsw;             // + c*128 ^ (kk<<6) + ot*8192
  int h1wo = w * 2048 + n15 * 128 + qlo8 + qhx + swd32;  // ^ (it<<5)
  int h1ro = w * 2048 + n15 * 128 + qx16 + hsw;          // ^ (kk<<6)

  f32x4 acc2[2][8];
#pragma unroll
  for (int a = 0; a < 2; ++a)
#pragma unroll
    for (int b = 0; b < 8; ++b) acc2[a][b] = (f32x4){0.f, 0.f, 0.f, 0.f};

  for (int c = 0; c < NCH; ++c) {
    // wa fragments first (latency hides under G1)
    bf16x8 wa[8][2];
    int wabase = wao + c * 128;
#pragma unroll
    for (int kk = 0; kk < 2; ++kk) {
      int p = wabase ^ (kk << 6);
#pragma unroll
      for (int ot = 0; ot < 8; ++ot)
        wa[ot][kk] = *(const bf16x8*)(wac8 + p + ot * 8192);
    }

    // bias (L2-hot global; issued early)
    const float* b1c = b1 + node * M1_ + c * CI;
    f32x4 bs[4];
#pragma unroll
    for (int it = 0; it < 4; ++it)
      bs[it] = (*(const f32x4*)(b1c + it * 16 + q * 4)) * (-LOG2E);

    // GEMM1
    f32x4 acc1[4][2];
#pragma unroll
    for (int a = 0; a < 4; ++a) {
      acc1[a][0] = (f32x4){0.f, 0.f, 0.f, 0.f};
      acc1[a][1] = (f32x4){0.f, 0.f, 0.f, 0.f};
    }
    int w1base = w1o + c * 16384;
#pragma unroll
    for (int kk = 0; kk < 4; ++kk) {
      int p = w1base ^ (kk << 6);
#pragma unroll
      for (int it = 0; it < 4; ++it) {
        bf16x8 wf = *(const bf16x8*)(w1c8 + p + it * 4096);
        acc1[it][0] = MFMA16(wf, xa[0][kk], acc1[it][0]);
        acc1[it][1] = MFMA16(wf, xa[1][kk], acc1[it][1]);
      }
    }

    // sig(mt0) -> write0 -> sig(mt1) -> read0+G2(mt0) -> write1 -> read1+G2(mt1)
    short4v s4a[4], s4b[4];
#pragma unroll
    for (int it = 0; it < 4; ++it) s4a[it] = pack_sig4(acc1[it][0], bs[it]);
#pragma unroll
    for (int it = 0; it < 4; ++it)
      *(short4v*)(h1c8 + (h1wo ^ (it << 5))) = s4a[it];
#pragma unroll
    for (int it = 0; it < 4; ++it) s4b[it] = pack_sig4(acc1[it][1], bs[it]);

    bf16x8 ha0[2];
#pragma unroll
    for (int kk = 0; kk < 2; ++kk)
      ha0[kk] = *(const bf16x8*)(h1c8 + (h1ro ^ (kk << 6)));
#pragma unroll
    for (int kk = 0; kk < 2; ++kk)
#pragma unroll
      for (int ot = 0; ot < 8; ++ot)
        acc2[0][ot] = MFMA16(ha0[kk], wa[ot][kk], acc2[0][ot]);

#pragma unroll
    for (int it = 0; it < 4; ++it)
      *(short4v*)(h1c8 + (h1wo ^ (it << 5))) = s4b[it];

    bf16x8 ha1[2];
#pragma unroll
    for (int kk = 0; kk < 2; ++kk)
      ha1[kk] = *(const bf16x8*)(h1c8 + (h1ro ^ (kk << 6)));
#pragma unroll
    for (int kk = 0; kk < 2; ++kk)
#pragma unroll
      for (int ot = 0; ot < 8; ++ot)
        acc2[1][ot] = MFMA16(ha1[kk], wa[ot][kk], acc2[1][ot]);
  }

  // ---- epilogue: sigmoid(h2 + ba) * Wb, reduce over o, store ----
  const float* ban = ba + node * M2_;
  const float* wbn = Wb + node * M2_;
  float bbv = bb[node];
  float bas[8], wbs[8];
#pragma unroll
  for (int ot = 0; ot < 8; ++ot) {
    int o = ot * 16 + n15;
    bas[ot] = ban[o] * (-LOG2E);
    wbs[ot] = wbn[o];
  }
#pragma unroll
  for (int mt = 0; mt < 2; ++mt) {
    f32x4 rs = (f32x4){0.f, 0.f, 0.f, 0.f};
#pragma unroll
    for (int ot = 0; ot < 8; ++ot)
#pragma unroll
      for (int r = 0; r < 4; ++r)
        rs[r] += sigmoid_pre(acc2[mt][ot][r], bas[ot]) * wbs[ot];
#pragma unroll
    for (int r = 0; r < 4; ++r) {
      float v = rs[r];
      v += __shfl_xor(v, 1);
      v += __shfl_xor(v, 2);
      v += __shfl_xor(v, 4);
      v += __shfl_xor(v, 8);
      if (n15 == 0)
        out[(size_t)(b0 + w * 32 + mt * 16 + q * 4 + r) * D_NODES + node] = v + bbv;
    }
  }
}

extern "C" void kernel_launch(void* const* d_in, const int* in_sizes, int n_in,
                              void* d_out, int out_size, void* d_ws, size_t ws_size,
                              hipStream_t stream) {
  const float* x  = (const float*)d_in[0];
  const float* W1 = (const float*)d_in[1];
  const float* b1 = (const float*)d_in[2];
  const float* Wa = (const float*)d_in[3];
  const float* ba = (const float*)d_in[4];
  const float* Wb = (const float*)d_in[5];
  const float* bb = (const float*)d_in[6];
  float* out = (float*)d_out;

  const size_t W1_ELEMS = (size_t)D_NODES * M1_ * KD;   // 4194304
  const size_t WA_ELEMS = (size_t)D_NODES * M1_ * M2_;  // 4194304
  const size_t X_ELEMS  = (size_t)B_ * KD;              // 524288
  const size_t NEED = (W1_ELEMS + WA_ELEMS + X_ELEMS) * sizeof(short);

  const int GRID = D_NODES * (B_ / BM);  // 2048

  if (ws_size >= NEED) {
    short* w1b = (short*)d_ws;
    short* waT = w1b + W1_ELEMS;
    short* xb  = waT + WA_ELEMS;
    cvt_f2b_k<<<(int)(W1_ELEMS / 1024), 256, 0, stream>>>(W1, w1b);
    cvt_f2b_k<<<(int)(X_ELEMS / 1024), 256, 0, stream>>>(x, xb);
    trans_wa_k<<<D_NODES * 4, 256, 0, stream>>>(Wa, waT);
    fused_dag_k<true><<<GRID, 512, 0, stream>>>(x, W1, b1, Wa, ba, Wb, bb, out,
                                                w1b, waT, xb);
  } else {
    fused_dag_k<false><<<GRID, 512, 0, stream>>>(x, W1, b1, Wa, ba, Wb, bb, out,
                                                 nullptr, nullptr, nullptr);
  }
}